// Round 3
// baseline (206.926 us; speedup 1.0000x reference)
//
#include <hip/hip_runtime.h>

// VectorQuantizer (VQ-VAE quantize) for MI355X.
// d_in[0] = x [65536 x 64] f32, d_in[1] = embedding [512 x 64] f32
// d_out   = [loss(1) | quantized(4194304) | indices-as-float(65536)] f32
//
// The grader's "np" reference computes d in FLOAT32 verbatim:
//   d = np.sum(x*x,1,keepdims=True) - (2.0*x) @ emb.T + np.sum(e*e,1)[None,:]
// so near-tie rows (gap < ulp(|x|^2) ~ 7.6e-6, ~0.4% of rows) are decided by the
// exact fp32 rounding sequence.  We replicate it bit-exactly:
//  - sums of squares: numpy pairwise (AVX512: 4x16-lane accs + reduce tree)
//  - matmul: sgemm-style sequential k-ordered FMA chain (x2 scaling is exact)
//  - d = fl(fl(A - 2M) + C), argmin first-min.
// fp contraction is disabled in the critical code (hipcc would otherwise fuse).

#define N_ROWS 65536
#define K_CODES 512
#define DIM 64
#define CHUNK 128   // codes staged in LDS per iteration (32 KiB)
#define KPER 32     // codes per thread per chunk (4-way k-split per row)

// numpy fp32 pairwise sum of a[j]*a[j], n=64, AVX512 path:
// sum0..3 = 16-lane blocks; lane_j = (p_j + p_{j+16}) + (p_{j+32} + p_{j+48});
// then _mm512_reduce_add_ps tree: (+8)(+4)(+2)(+1).
__device__ __forceinline__ float np_sumsq64(const float* __restrict__ a) {
#pragma clang fp contract(off)
    float lane[16];
#pragma unroll
    for (int j = 0; j < 16; ++j) {
        float p0 = __fmul_rn(a[j],      a[j]);
        float p1 = __fmul_rn(a[j + 16], a[j + 16]);
        float p2 = __fmul_rn(a[j + 32], a[j + 32]);
        float p3 = __fmul_rn(a[j + 48], a[j + 48]);
        lane[j] = __fadd_rn(__fadd_rn(p0, p1), __fadd_rn(p2, p3));
    }
    float u[8];
#pragma unroll
    for (int j = 0; j < 8; ++j) u[j] = __fadd_rn(lane[j], lane[j + 8]);
    float v[4];
#pragma unroll
    for (int j = 0; j < 4; ++j) v[j] = __fadd_rn(u[j], u[j + 4]);
    return __fadd_rn(__fadd_rn(v[0], v[2]), __fadd_rn(v[1], v[3]));
}

__global__ __launch_bounds__(256) void vq_argmin_np32(
    const float* __restrict__ x, const float* __restrict__ emb,
    float* __restrict__ idx_out)
{
#pragma clang fp contract(off)
    __shared__ float se[CHUNK * DIM];  // 32 KiB, float4-slot XOR-swizzled
    __shared__ float sn[CHUNK];        // np-fp32 |e_k|^2

    const int tid = threadIdx.x;
    const int q = tid & 3;                       // k-split id (4 per row)
    const int row = blockIdx.x * 64 + (tid >> 2);

    float xs[DIM];
    const float4* xrow = reinterpret_cast<const float4*>(x + row * DIM);
#pragma unroll
    for (int j = 0; j < 16; ++j) {
        float4 w = xrow[j];
        xs[4 * j + 0] = w.x; xs[4 * j + 1] = w.y;
        xs[4 * j + 2] = w.z; xs[4 * j + 3] = w.w;
    }
    const float A = np_sumsq64(xs);

    float best_d = 1e30f;
    int best_k = 0;

    for (int c = 0; c < K_CODES / CHUNK; ++c) {
        __syncthreads();  // protect previous chunk
        // cooperative staging, swizzle float4 slot by code bits 5-6 so the 4
        // k-split lanes later read distinct bank quads (broadcast within 16)
        const float4* esrc = reinterpret_cast<const float4*>(emb + c * CHUNK * DIM);
        float4* sdst = reinterpret_cast<float4*>(se);
#pragma unroll
        for (int t = 0; t < 8; ++t) {
            int g = t * 256 + tid;          // float4 index in chunk
            int code = g >> 4, j = g & 15;
            sdst[code * 16 + (j ^ ((code >> 5) & 3))] = esrc[g];
        }
        if (tid < CHUNK)
            sn[tid] = np_sumsq64(emb + (c * CHUNK + tid) * DIM);
        __syncthreads();

        const float4* se4 = reinterpret_cast<const float4*>(se);
        for (int i = 0; i < KPER; ++i) {
            const int lc = q * KPER + i;            // (lc>>5)&3 == q
            const float4* e4 = se4 + lc * 16;
            float m = 0.f;                          // sgemm k-ordered FMA chain
#pragma unroll
            for (int j = 0; j < 16; ++j) {
                float4 e = e4[j ^ q];
                m = __fmaf_rn(xs[4 * j + 0], e.x, m);
                m = __fmaf_rn(xs[4 * j + 1], e.y, m);
                m = __fmaf_rn(xs[4 * j + 2], e.z, m);
                m = __fmaf_rn(xs[4 * j + 3], e.w, m);
            }
            // d = fl(fl(A - 2M) + C); 2*M is exact
            float d = __fadd_rn(__fsub_rn(A, __fmul_rn(2.0f, m)), sn[lc]);
            int k = c * CHUNK + lc;
            if (d < best_d) { best_d = d; best_k = k; }  // first-min in k order
        }
    }

    // reduce across the 4 k-split lanes: smaller d, tie -> smaller k
#pragma unroll
    for (int off = 1; off < 4; off <<= 1) {
        float od = __shfl_xor(best_d, off, 64);
        int   ok = __shfl_xor(best_k, off, 64);
        if (od < best_d || (od == best_d && ok < best_k)) { best_d = od; best_k = ok; }
    }
    if (q == 0) idx_out[row] = (float)best_k;
}

// gather quantized rows, write quantized, accumulate loss partials
__global__ __launch_bounds__(256) void vq_gather_kernel(
    const float* __restrict__ x, const float* __restrict__ emb,
    const float* __restrict__ idx_f, float* __restrict__ out_q /* d_out+1 */,
    double* __restrict__ acc)
{
    const int g = blockIdx.x * 256 + threadIdx.x;  // one float4 of quantized
    const int n = g >> 4, d4 = g & 15;
    const int idx = (int)idx_f[n];
    float4 e = reinterpret_cast<const float4*>(emb)[idx * (DIM / 4) + d4];
    float4 xi = reinterpret_cast<const float4*>(x)[g];

    // out_q is d_out+1 -> only 4B aligned; scalar stores
    float* o = out_q + g * 4;
    o[0] = e.x; o[1] = e.y; o[2] = e.z; o[3] = e.w;

    float dx = e.x - xi.x, dy = e.y - xi.y, dz = e.z - xi.z, dw = e.w - xi.w;
    float s = dx * dx + dy * dy + dz * dz + dw * dw;

#pragma unroll
    for (int off = 32; off > 0; off >>= 1) s += __shfl_down(s, off, 64);

    __shared__ double bs[4];
    const int lane = threadIdx.x & 63, wid = threadIdx.x >> 6;
    if (lane == 0) bs[wid] = (double)s;
    __syncthreads();
    if (threadIdx.x == 0) {
        double t = (bs[0] + bs[1]) + (bs[2] + bs[3]);
        atomicAdd(acc, t);
    }
}

__global__ void vq_finalize_kernel(const double* __restrict__ acc,
                                   float* __restrict__ out0)
{
    double mean = acc[0] / (double)(N_ROWS * DIM);
    out0[0] = (float)(1.25 * mean);  // q_latent + 0.25*e_latent (numerically equal)
}

extern "C" void kernel_launch(void* const* d_in, const int* in_sizes, int n_in,
                              void* d_out, int out_size, void* d_ws, size_t ws_size,
                              hipStream_t stream)
{
    const float* x   = (const float*)d_in[0];
    const float* emb = (const float*)d_in[1];
    float* out = (float*)d_out;
    double* acc = (double*)d_ws;

    hipMemsetAsync(d_ws, 0, 8, stream);  // ws re-poisoned 0xAA each launch

    float* out_q = out + 1;                 // quantized region
    float* idx_f = out + 1 + N_ROWS * DIM;  // indices region (as float)

    vq_argmin_np32<<<N_ROWS / 64, 256, 0, stream>>>(x, emb, idx_f);
    vq_gather_kernel<<<(N_ROWS * DIM / 4) / 256, 256, 0, stream>>>(x, emb, idx_f,
                                                                   out_q, acc);
    vq_finalize_kernel<<<1, 1, 0, stream>>>(acc, out);
}

// Round 5
// 164.598 us; speedup vs baseline: 1.2572x; 1.2572x over previous
//
#include <hip/hip_runtime.h>

// VectorQuantizer (VQ-VAE quantize) for MI355X — R4: LDS-free main loop.
// d_in[0] = x [65536 x 64] f32, d_in[1] = embedding [512 x 64] f32
// d_out   = [loss(1) | quantized(4194304) | indices-as-float(65536)] f32
//
// Grader's "np" ref computes d in FLOAT32 verbatim:
//   d = sum(x*x,1) - (2x) @ emb.T + sum(e*e,1)
// Near-tie rows (~0.4%) are decided by exact fp32 rounding. We replicate
// bit-exactly (verified PASS in R3):
//  - sums of squares: numpy pairwise AVX512 tree
//  - matmul: sequential k-ordered FMA chain (x2 exact)
//  - d = fl(fl(A-2M)+C), first-min argmin, (d,k) tie-break across splits.
//
// R4 structure: lanes = rows, so e is wave-uniform per code -> broadcast
// loads from global (no LDS in main loop; R3 was LDS-BW-bound at 8.6 GB).
// k-split 4 across the block's waves; gather+loss fused into epilogue.

#define N_ROWS 65536
#define K_CODES 512
#define DIM 64

// numpy fp32 pairwise sum of a[j]^2, n=64 (AVX512 path: 4x16-lane blocks,
// lane_j = (p_j+p_{j+16}) + (p_{j+32}+p_{j+48}); then reduce tree +8+4+2+1).
__device__ __forceinline__ float np_sumsq64(const float* a) {
#pragma clang fp contract(off)
    float lane[16];
#pragma unroll
    for (int j = 0; j < 16; ++j) {
        float p0 = __fmul_rn(a[j],      a[j]);
        float p1 = __fmul_rn(a[j + 16], a[j + 16]);
        float p2 = __fmul_rn(a[j + 32], a[j + 32]);
        float p3 = __fmul_rn(a[j + 48], a[j + 48]);
        lane[j] = __fadd_rn(__fadd_rn(p0, p1), __fadd_rn(p2, p3));
    }
    float u[8];
#pragma unroll
    for (int j = 0; j < 8; ++j) u[j] = __fadd_rn(lane[j], lane[j + 8]);
    float v[4];
#pragma unroll
    for (int j = 0; j < 4; ++j) v[j] = __fadd_rn(u[j], u[j + 4]);
    return __fadd_rn(__fadd_rn(v[0], v[2]), __fadd_rn(v[1], v[3]));
}

__global__ __launch_bounds__(256, 4) void vq_fused(
    const float* __restrict__ x, const float* __restrict__ emb,
    float* __restrict__ out_q /* d_out+1 */,
    float* __restrict__ idx_out, double* __restrict__ acc)
{
#pragma clang fp contract(off)
    __shared__ float sn[K_CODES];        // np |e_k|^2, 2 KiB
    __shared__ float rd[4][64];          // per-wave best d
    __shared__ int   rk[4][64];          // per-wave best k
    __shared__ int   kfin[64];
    __shared__ float qbuf[64 * DIM];     // 16 KiB staged quantized tile
    __shared__ double bs[4];

    const int tid = threadIdx.x;
    const int w = tid >> 6, l = tid & 63;
    const int row = blockIdx.x * 64 + l;

    // per-block |e_k|^2 precompute (2 codes/thread, one-time)
    for (int c = tid; c < K_CODES; c += 256)
        sn[c] = np_sumsq64(emb + c * DIM);

    // x row -> 64 VGPRs
    float xs[DIM];
    const float4* xrow = reinterpret_cast<const float4*>(x + (size_t)row * DIM);
#pragma unroll
    for (int j = 0; j < 16; ++j) {
        float4 v = xrow[j];
        xs[4 * j + 0] = v.x; xs[4 * j + 1] = v.y;
        xs[4 * j + 2] = v.z; xs[4 * j + 3] = v.w;
    }
    const float A = np_sumsq64(xs);
    __syncthreads();

    // main loop: this wave's 128 codes, processed in pairs (2 indep chains)
    float best_d = 1e30f;
    int best_k = 0;
    const int k0 = w * 128;
    for (int i = 0; i < 128; i += 2) {
        // force wave-uniform (SGPR) code index -> scalar/broadcast e loads
        const int ka = __builtin_amdgcn_readfirstlane(k0 + i);
        const int kb = ka + 1;
        const float4* ea = reinterpret_cast<const float4*>(emb + ka * DIM);
        const float4* eb = reinterpret_cast<const float4*>(emb + kb * DIM);
        float ma = 0.f, mb = 0.f;  // sgemm-order sequential FMA chains
#pragma unroll
        for (int j = 0; j < 16; ++j) {
            float4 a4 = ea[j];
            float4 b4 = eb[j];
            ma = __fmaf_rn(xs[4 * j + 0], a4.x, ma);
            ma = __fmaf_rn(xs[4 * j + 1], a4.y, ma);
            ma = __fmaf_rn(xs[4 * j + 2], a4.z, ma);
            ma = __fmaf_rn(xs[4 * j + 3], a4.w, ma);
            mb = __fmaf_rn(xs[4 * j + 0], b4.x, mb);
            mb = __fmaf_rn(xs[4 * j + 1], b4.y, mb);
            mb = __fmaf_rn(xs[4 * j + 2], b4.z, mb);
            mb = __fmaf_rn(xs[4 * j + 3], b4.w, mb);
        }
        // d = fl(fl(A - 2M) + C); 2*M exact
        float da = __fadd_rn(__fsub_rn(A, __fmul_rn(2.0f, ma)), sn[ka]);
        float db = __fadd_rn(__fsub_rn(A, __fmul_rn(2.0f, mb)), sn[kb]);
        if (da < best_d) { best_d = da; best_k = ka; }  // first-min: ka < kb
        if (db < best_d) { best_d = db; best_k = kb; }
    }

    // cross-wave (k-split) reduce: smaller d, tie -> smaller k
    rd[w][l] = best_d; rk[w][l] = best_k;
    __syncthreads();
    if (w == 0) {
        float bd = rd[0][l]; int bk = rk[0][l];
#pragma unroll
        for (int q = 1; q < 4; ++q) {
            float od = rd[q][l]; int ok = rk[q][l];
            if (od < bd || (od == bd && ok < bk)) { bd = od; bk = ok; }
        }
        kfin[l] = bk;
        idx_out[row] = (float)bk;   // coalesced, lanes = consecutive rows
    }
    __syncthreads();

    // gather chosen code rows into LDS (coalesced 256B per 16-lane group)
    float4* qb4 = reinterpret_cast<float4*>(qbuf);
    const float4* e4 = reinterpret_cast<const float4*>(emb);
#pragma unroll
    for (int i = 0; i < 4; ++i) {
        int pg = i * 256 + tid;          // float4 piece in 64x64 tile
        int r = pg >> 4, j = pg & 15;
        qb4[pg] = e4[kfin[r] * (DIM / 4) + j];
    }
    __syncthreads();

    // write quantized (out_q only 4B-aligned -> dword stores, fully coalesced)
    // + loss partial: sum (q - x)^2 over the tile
    const int base = blockIdx.x * 64 * DIM;
    float s = 0.f;
#pragma unroll
    for (int i = 0; i < 16; ++i) {
        int idx = i * 256 + tid;
        float qv = qbuf[idx];
        float xv = x[base + idx];
        out_q[base + idx] = qv;
        float dq = __fsub_rn(qv, xv);
        s = __fmaf_rn(dq, dq, s);
    }
    double sd = (double)s;
#pragma unroll
    for (int off = 32; off > 0; off >>= 1) sd += __shfl_down(sd, off, 64);
    if (l == 0) bs[w] = sd;
    __syncthreads();
    if (tid == 0) atomicAdd(acc, (bs[0] + bs[1]) + (bs[2] + bs[3]));
}

__global__ void vq_finalize_kernel(const double* __restrict__ acc,
                                   float* __restrict__ out0)
{
    double mean = acc[0] / (double)(N_ROWS * DIM);
    out0[0] = (float)(1.25 * mean);  // q_latent + 0.25*e_latent (equal)
}

extern "C" void kernel_launch(void* const* d_in, const int* in_sizes, int n_in,
                              void* d_out, int out_size, void* d_ws, size_t ws_size,
                              hipStream_t stream)
{
    const float* x   = (const float*)d_in[0];
    const float* emb = (const float*)d_in[1];
    float* out = (float*)d_out;
    double* acc = (double*)d_ws;

    hipMemsetAsync(d_ws, 0, 8, stream);  // ws re-poisoned 0xAA each launch

    float* out_q = out + 1;                 // quantized region
    float* idx_f = out + 1 + N_ROWS * DIM;  // indices region (as float)

    vq_fused<<<N_ROWS / 64, 256, 0, stream>>>(x, emb, out_q, idx_f, acc);
    vq_finalize_kernel<<<1, 1, 0, stream>>>(acc, out);
}

// Round 6
// 120.654 us; speedup vs baseline: 1.7150x; 1.3642x over previous
//
#include <hip/hip_runtime.h>

// VectorQuantizer (VQ-VAE quantize) for MI355X — R6: MFMA candidate scan +
// exact np-fp32 rescore of near-ties.
// d_in[0] = x [65536 x 64] f32, d_in[1] = embedding [512 x 64] f32
// d_out   = [loss(1) | quantized(4194304) | indices-as-float(65536)] f32
//
// Grader's "np" ref computes d in FLOAT32: d = A - (2x)@e.T + C.
// R3/R5 verified the bit-exact emulation (np pairwise sums of squares, the
// sequential k-ordered FMA chain, d = fl(fl(A-2M)+C), first-min argmin).
// R6 replaces the exhaustive fp32 VALU scan (27us issue floor, measured
// 105us) with a bf16-split MFMA scan (matrix pipe) + margin filter:
//   d~ = C - 2*(xh.eh + xl.eh + xh.el)   (A is row-constant -> dropped)
//   |d~ - (np_d - A)| <= eps(split ~3e-6) + eta(np rounding ~1.5e-5)
// Candidates within MARGIN=1e-4 of the row min provably contain the
// np-argmin; rows with 1 candidate are done, rows with >=2 (~3%) get the
// verified exact np chain on original fp32 data.

#define N_ROWS 65536
#define K_CODES 512
#define DIM 64
#define MARGIN 1e-4f

typedef short short8 __attribute__((ext_vector_type(8)));
typedef float f32x4 __attribute__((ext_vector_type(4)));

__device__ __forceinline__ unsigned short bf16_rne(float f) {
    unsigned u = __builtin_bit_cast(unsigned, f);
    u += 0x7FFFu + ((u >> 16) & 1u);
    return (unsigned short)(u >> 16);
}
__device__ __forceinline__ float bf16_f32(unsigned short h) {
    unsigned u = (unsigned)h << 16;
    return __builtin_bit_cast(float, u);
}

// numpy fp32 pairwise sum of a[j]^2, n=64 (AVX512 path) — verified R3/R5.
__device__ __forceinline__ float np_sumsq64(const float* a) {
#pragma clang fp contract(off)
    float lane[16];
#pragma unroll
    for (int j = 0; j < 16; ++j) {
        float p0 = __fmul_rn(a[j],      a[j]);
        float p1 = __fmul_rn(a[j + 16], a[j + 16]);
        float p2 = __fmul_rn(a[j + 32], a[j + 32]);
        float p3 = __fmul_rn(a[j + 48], a[j + 48]);
        lane[j] = __fadd_rn(__fadd_rn(p0, p1), __fadd_rn(p2, p3));
    }
    float u[8];
#pragma unroll
    for (int j = 0; j < 8; ++j) u[j] = __fadd_rn(lane[j], lane[j + 8]);
    float v[4];
#pragma unroll
    for (int j = 0; j < 4; ++j) v[j] = __fadd_rn(u[j], u[j + 4]);
    return __fadd_rn(__fadd_rn(v[0], v[2]), __fadd_rn(v[1], v[3]));
}

// prep: emb -> bf16 hi/lo split tables + exact np |e|^2
__global__ __launch_bounds__(256) void vq_prep(
    const float* __restrict__ emb, unsigned short* __restrict__ ehT,
    unsigned short* __restrict__ elT, float* __restrict__ snp)
{
    const int c = blockIdx.x * 256 + threadIdx.x;
    if (c >= K_CODES) return;
    float ev[DIM];
    const float4* e4 = reinterpret_cast<const float4*>(emb + c * DIM);
#pragma unroll
    for (int j = 0; j < 16; ++j) {
        float4 v = e4[j];
        ev[4*j+0] = v.x; ev[4*j+1] = v.y; ev[4*j+2] = v.z; ev[4*j+3] = v.w;
    }
    snp[c] = np_sumsq64(ev);
#pragma unroll
    for (int j = 0; j < DIM; ++j) {
        unsigned short h = bf16_rne(ev[j]);
        ehT[c * DIM + j] = h;
        elT[c * DIM + j] = bf16_rne(__fsub_rn(ev[j], bf16_f32(h)));
    }
}

__global__ __launch_bounds__(256, 1) void vq_main(
    const float* __restrict__ x, const float* __restrict__ emb,
    const unsigned short* __restrict__ ehT, const unsigned short* __restrict__ elT,
    const float* __restrict__ snp, float* __restrict__ out_q /* d_out+1 */,
    float* __restrict__ idx_out, double* __restrict__ acc)
{
#pragma clang fp contract(off)
    __shared__ unsigned short xh[64 * DIM];   // 8 KB bf16-hi of x tile
    __shared__ unsigned short xl[64 * DIM];   // 8 KB bf16-lo
    __shared__ float sn[K_CODES];             // 2 KB np |e|^2
    __shared__ float Anp[64];                 // exact np |x|^2 per row
    __shared__ float rmw[4][64];              // per-wave row minima
    __shared__ float rowmin[64];
    __shared__ int   ccnt[64];
    __shared__ int   ck[64][16];              // candidate code lists
    __shared__ int   kfin[64];
    __shared__ float qbuf[64 * DIM];          // 16 KB quantized tile
    __shared__ double bs[4];

    const int tid = threadIdx.x;
    const int w = tid >> 6, l = tid & 63;
    const int g16 = l >> 4, c16 = l & 15;
    const size_t rowbase = (size_t)blockIdx.x * 64;

    // stage x -> bf16 split in LDS (coalesced float4 loads)
    const float4* x4 = reinterpret_cast<const float4*>(x + rowbase * DIM);
#pragma unroll
    for (int i = 0; i < 4; ++i) {
        int g = i * 256 + tid;            // float4 index in 64x64 tile
        float4 v = x4[g];
        float vv[4] = {v.x, v.y, v.z, v.w};
        int base = g * 4;
#pragma unroll
        for (int e = 0; e < 4; ++e) {
            unsigned short h = bf16_rne(vv[e]);
            xh[base + e] = h;
            xl[base + e] = bf16_rne(__fsub_rn(vv[e], bf16_f32(h)));
        }
    }
    for (int c = tid; c < K_CODES; c += 256) sn[c] = snp[c];
    if (tid < 64) {
        ccnt[tid] = 0;
        float xv[DIM];
        const float4* xr = reinterpret_cast<const float4*>(x + (rowbase + tid) * DIM);
#pragma unroll
        for (int j = 0; j < 16; ++j) {
            float4 v = xr[j];
            xv[4*j+0] = v.x; xv[4*j+1] = v.y; xv[4*j+2] = v.z; xv[4*j+3] = v.w;
        }
        Anp[tid] = np_sumsq64(xv);
    }
    __syncthreads();

    // A-frags: lane supplies x[rt*16 + c16][kstep*32 + g16*8 .. +7]
    short8 ah[4][2], al[4][2];
#pragma unroll
    for (int rt = 0; rt < 4; ++rt)
#pragma unroll
        for (int s = 0; s < 2; ++s) {
            int off = (rt * 16 + c16) * DIM + s * 32 + g16 * 8;
            ah[rt][s] = *reinterpret_cast<const short8*>(xh + off);
            al[rt][s] = *reinterpret_cast<const short8*>(xl + off);
        }

    // MFMA scan: wave w covers codes [w*128, w*128+128), 8 col-tiles
    float dv[4][8][4];
    const int wc0 = w * 128;
#pragma unroll
    for (int ct = 0; ct < 8; ++ct) {
        const int cb = wc0 + ct * 16;
        short8 bh[2], bl[2];
#pragma unroll
        for (int s = 0; s < 2; ++s) {
            int off = (cb + c16) * DIM + s * 32 + g16 * 8;
            bh[s] = *reinterpret_cast<const short8*>(ehT + off);
            bl[s] = *reinterpret_cast<const short8*>(elT + off);
        }
        const float snk = sn[cb + c16];
#pragma unroll
        for (int rt = 0; rt < 4; ++rt) {
            f32x4 a = {0.f, 0.f, 0.f, 0.f};
#pragma unroll
            for (int s = 0; s < 2; ++s) {
                a = __builtin_amdgcn_mfma_f32_16x16x32_bf16(ah[rt][s], bh[s], a, 0, 0, 0);
                a = __builtin_amdgcn_mfma_f32_16x16x32_bf16(al[rt][s], bh[s], a, 0, 0, 0);
                a = __builtin_amdgcn_mfma_f32_16x16x32_bf16(ah[rt][s], bl[s], a, 0, 0, 0);
            }
#pragma unroll
            for (int r = 0; r < 4; ++r)
                dv[rt][ct][r] = __fmaf_rn(-2.f, a[r], snk);  // C - 2M~
        }
    }

    // per-row min: lane-local over ct, then across the 16-lane col group
    float lmin[4][4];
#pragma unroll
    for (int rt = 0; rt < 4; ++rt)
#pragma unroll
        for (int r = 0; r < 4; ++r) {
            float m = dv[rt][0][r];
#pragma unroll
            for (int ct = 1; ct < 8; ++ct) m = fminf(m, dv[rt][ct][r]);
            lmin[rt][r] = m;
        }
#pragma unroll
    for (int msk = 1; msk < 16; msk <<= 1)
#pragma unroll
        for (int rt = 0; rt < 4; ++rt)
#pragma unroll
            for (int r = 0; r < 4; ++r)
                lmin[rt][r] = fminf(lmin[rt][r], __shfl_xor(lmin[rt][r], msk, 64));
    if (c16 == 0)
#pragma unroll
        for (int rt = 0; rt < 4; ++rt)
#pragma unroll
            for (int r = 0; r < 4; ++r)
                rmw[w][rt * 16 + g16 * 4 + r] = lmin[rt][r];
    __syncthreads();
    if (tid < 64)
        rowmin[tid] = fminf(fminf(rmw[0][tid], rmw[1][tid]),
                            fminf(rmw[2][tid], rmw[3][tid]));
    __syncthreads();

    // candidate append (np-argmin provably within MARGIN of row min)
#pragma unroll
    for (int rt = 0; rt < 4; ++rt)
#pragma unroll
        for (int ct = 0; ct < 8; ++ct)
#pragma unroll
            for (int r = 0; r < 4; ++r) {
                int row = rt * 16 + g16 * 4 + r;
                if (dv[rt][ct][r] <= rowmin[row] + MARGIN) {
                    int pos = atomicAdd(&ccnt[row], 1);
                    if (pos < 16) ck[row][pos] = wc0 + ct * 16 + c16;
                }
            }
    __syncthreads();

    // rescore: 1 candidate -> done; >=2 -> exact np-fp32 chain (verified R3/R5)
    if (tid < 64) {
        const int cnt = ccnt[tid];
        int k;
        if (cnt == 1) {
            k = ck[tid][0];
        } else {
            float xv[DIM];
            const float4* xr = reinterpret_cast<const float4*>(x + (rowbase + tid) * DIM);
#pragma unroll
            for (int j = 0; j < 16; ++j) {
                float4 v = xr[j];
                xv[4*j+0] = v.x; xv[4*j+1] = v.y; xv[4*j+2] = v.z; xv[4*j+3] = v.w;
            }
            const float A = Anp[tid];
            float bd = 1e30f; int bk = K_CODES;
            const int nlist = (cnt <= 16) ? cnt : K_CODES;  // overflow net
            for (int i = 0; i < nlist; ++i) {
                const int kk = (cnt <= 16) ? ck[tid][i] : i;
                const float* er = emb + kk * DIM;
                float m = 0.f;
#pragma unroll
                for (int j = 0; j < DIM; ++j) m = __fmaf_rn(xv[j], er[j], m);
                float d = __fadd_rn(__fsub_rn(A, __fmul_rn(2.0f, m)), sn[kk]);
                if (d < bd || (d == bd && kk < bk)) { bd = d; bk = kk; }
            }
            k = bk;
        }
        kfin[tid] = k;
        idx_out[rowbase + tid] = (float)k;   // coalesced
    }
    __syncthreads();

    // epilogue (verbatim from passing R5): gather + quantized write + loss
    float4* qb4 = reinterpret_cast<float4*>(qbuf);
    const float4* e4 = reinterpret_cast<const float4*>(emb);
#pragma unroll
    for (int i = 0; i < 4; ++i) {
        int pg = i * 256 + tid;
        int r = pg >> 4, j = pg & 15;
        qb4[pg] = e4[kfin[r] * (DIM / 4) + j];
    }
    __syncthreads();
    const int base = blockIdx.x * 64 * DIM;
    float s = 0.f;
#pragma unroll
    for (int i = 0; i < 16; ++i) {
        int idx = i * 256 + tid;
        float qv = qbuf[idx];
        float xv = x[base + idx];
        out_q[base + idx] = qv;
        float dq = __fsub_rn(qv, xv);
        s = __fmaf_rn(dq, dq, s);
    }
    double sd = (double)s;
#pragma unroll
    for (int off = 32; off > 0; off >>= 1) sd += __shfl_down(sd, off, 64);
    if (l == 0) bs[w] = sd;
    __syncthreads();
    if (tid == 0) atomicAdd(acc, (bs[0] + bs[1]) + (bs[2] + bs[3]));
}

__global__ void vq_finalize_kernel(const double* __restrict__ acc,
                                   float* __restrict__ out0)
{
    double mean = acc[0] / (double)(N_ROWS * DIM);
    out0[0] = (float)(1.25 * mean);  // q_latent + 0.25*e_latent (equal)
}

extern "C" void kernel_launch(void* const* d_in, const int* in_sizes, int n_in,
                              void* d_out, int out_size, void* d_ws, size_t ws_size,
                              hipStream_t stream)
{
    const float* x   = (const float*)d_in[0];
    const float* emb = (const float*)d_in[1];
    float* out = (float*)d_out;
    char* ws = (char*)d_ws;
    double* acc = (double*)ws;                                   // 8 B
    unsigned short* ehT = (unsigned short*)(ws + 4096);          // 64 KB
    unsigned short* elT = (unsigned short*)(ws + 4096 + 65536);  // 64 KB
    float* snp = (float*)(ws + 4096 + 131072);                   // 2 KB

    hipMemsetAsync(d_ws, 0, 8, stream);  // acc (ws re-poisoned each launch)

    float* out_q = out + 1;
    float* idx_f = out + 1 + (size_t)N_ROWS * DIM;

    vq_prep<<<2, 256, 0, stream>>>(emb, ehT, elT, snp);
    vq_main<<<N_ROWS / 64, 256, 0, stream>>>(x, emb, ehT, elT, snp,
                                             out_q, idx_f, acc);
    vq_finalize_kernel<<<1, 1, 0, stream>>>(acc, out);
}